// Round 5
// baseline (242.547 us; speedup 1.0000x reference)
//
#include <hip/hip_runtime.h>
#include <math.h>

#define THREADS 256
#define TILE    2048

// ---- monotone float <-> uint encoding (order-preserving) ----
__device__ __forceinline__ unsigned enc_f(float f) {
    unsigned b = __float_as_uint(f);
    return (b & 0x80000000u) ? ~b : (b | 0x80000000u);
}
__device__ __forceinline__ float dec_f(unsigned u) {
    unsigned b = (u & 0x80000000u) ? (u ^ 0x80000000u) : ~u;
    return __uint_as_float(b);
}
#define ENC_NEG_INF 0x007FFFFFu   // enc(-inf): identity for max
#define ENC_POS_INF 0xFF800000u   // enc(+inf): identity for min

// ws layout: unsigned ws[0..31] stats | double acc @ ws[32..33] | done @ ws[34]
// zc (compacted z, n floats) at byte offset 256 if ws_size permits.

__global__ void k_init(unsigned* __restrict__ ws) {
    int t = threadIdx.x;
    if (t < 32) ws[t] = (t < 8 || t >= 24) ? ENC_NEG_INF : ENC_POS_INF;
    else if (t == 32) { *(double*)(ws + 32) = 0.0; ws[34] = 0u; }
}

#define CNT_B(ii, bdst) do { bdst = 0; \
    _Pragma("unroll") for (int j_ = 0; j_ < 8; ++j_) bdst += ((ii) >= roff[j_]); } while (0)

#define FLUSH_TO(bb, g_, p_, mn_, mx_) do { \
    atomicMax(&s_stats[      (bb)], enc_f(g_));  \
    atomicMin(&s_stats[ 8  + (bb)], enc_f(p_));  \
    atomicMin(&s_stats[16  + (bb)], enc_f(mn_)); \
    atomicMax(&s_stats[24  + (bb)], enc_f(mx_)); } while (0)

__global__ __launch_bounds__(THREADS) void k_stats(
        const float* __restrict__ coord, const int* __restrict__ segment,
        const int* __restrict__ offset, unsigned* __restrict__ ws,
        float* __restrict__ zc, int n, int nb, int have_zc) {
    __shared__ float    s_c[TILE * 3];          // 24 KB raw coord tile
    __shared__ unsigned s_stats[32];
    const int tid = threadIdx.x;
    if (tid < 32) s_stats[tid] = (tid < 8 || tid >= 24) ? ENC_NEG_INF : ENC_POS_INF;
    int roff[8];
    #pragma unroll
    for (int j = 0; j < 8; ++j) roff[j] = (j < nb) ? offset[j] : 0x7FFFFFFF;

    const int start = blockIdx.x * TILE;
    const int end   = min(n, start + TILE);
    float lg = -INFINITY, lp = INFINITY, lmn = INFINITY, lmx = -INFINITY;
    int curb = -1, ba, bb;
    CNT_B(start, ba); CNT_B(end - 1, bb);
    const bool uni = (ba == bb);

    if (end - start == TILE) {
        // dense lane-contiguous staging: coord -> LDS, seg -> regs
        const float4* cg4 = (const float4*)coord + (((size_t)start * 3) >> 2);
        float4* s_c4 = (float4*)s_c;
        #pragma unroll
        for (int k = 0; k < 6; ++k) s_c4[tid + k * THREADS] = cg4[tid + k * THREADS];
        int4 sf[2];
        const int4* sg4 = (const int4*)segment + (start >> 2);
        #pragma unroll
        for (int k = 0; k < 2; ++k) sf[k] = sg4[tid + k * THREADS];
        __syncthreads();

        #pragma unroll
        for (int k = 0; k < 2; ++k) {
            const int q = tid + k * THREADS;       // local quad index
            const float z0 = s_c[12*q+2], z1 = s_c[12*q+5];
            const float z2 = s_c[12*q+8], z3 = s_c[12*q+11];
            if (have_zc)
                ((float4*)zc)[(start >> 2) + q] = make_float4(z0, z1, z2, z3);
            const int4 sg = sf[k];
            if (uni) {
                lmn = fminf(fminf(fminf(lmn, z0), z1), fminf(z2, z3));
                lmx = fmaxf(fmaxf(fmaxf(lmx, z0), z1), fmaxf(z2, z3));
                lg  = fmaxf(lg, (sg.x == 0) ? z0 : -INFINITY);
                lg  = fmaxf(lg, (sg.y == 0) ? z1 : -INFINITY);
                lg  = fmaxf(lg, (sg.z == 0) ? z2 : -INFINITY);
                lg  = fmaxf(lg, (sg.w == 0) ? z3 : -INFINITY);
                lp  = fminf(lp, (sg.x != 0) ? z0 : INFINITY);
                lp  = fminf(lp, (sg.y != 0) ? z1 : INFINITY);
                lp  = fminf(lp, (sg.z != 0) ? z2 : INFINITY);
                lp  = fminf(lp, (sg.w != 0) ? z3 : INFINITY);
            } else {
                float zz[4] = { z0, z1, z2, z3 };
                int   ss[4] = { sg.x, sg.y, sg.z, sg.w };
                #pragma unroll
                for (int jj = 0; jj < 4; ++jj) {
                    int i = start + 4*q + jj, b;
                    CNT_B(i, b);
                    if (b != curb) {
                        if (curb >= 0) FLUSH_TO(curb, lg, lp, lmn, lmx);
                        lg = -INFINITY; lp = INFINITY; lmn = INFINITY; lmx = -INFINITY;
                        curb = b;
                    }
                    lmn = fminf(lmn, zz[jj]); lmx = fmaxf(lmx, zz[jj]);
                    if (ss[jj] == 0) lg = fmaxf(lg, zz[jj]); else lp = fminf(lp, zz[jj]);
                }
            }
        }
        if (uni) {
            #pragma unroll
            for (int m = 32; m; m >>= 1) {
                lg  = fmaxf(lg,  __shfl_xor(lg,  m, 64));
                lp  = fminf(lp,  __shfl_xor(lp,  m, 64));
                lmn = fminf(lmn, __shfl_xor(lmn, m, 64));
                lmx = fmaxf(lmx, __shfl_xor(lmx, m, 64));
            }
            if ((tid & 63) == 0) FLUSH_TO(ba, lg, lp, lmn, lmx);
        } else if (curb >= 0) {
            FLUSH_TO(curb, lg, lp, lmn, lmx);
        }
    } else {
        // scalar guarded tail block
        for (int i = start + tid; i < end; i += THREADS) {
            float z = coord[3*i + 2]; int s = segment[i], b;
            if (have_zc) zc[i] = z;
            CNT_B(i, b);
            if (b != curb) {
                if (curb >= 0) FLUSH_TO(curb, lg, lp, lmn, lmx);
                lg = -INFINITY; lp = INFINITY; lmn = INFINITY; lmx = -INFINITY;
                curb = b;
            }
            lmn = fminf(lmn, z); lmx = fmaxf(lmx, z);
            if (s == 0) lg = fmaxf(lg, z); else lp = fminf(lp, z);
        }
        if (curb >= 0) FLUSH_TO(curb, lg, lp, lmn, lmx);
        __syncthreads();   // match the full path's single pre-flush barrier count
    }
    __syncthreads();
    if (tid < 32) {
        unsigned v = s_stats[tid];
        unsigned ident = (tid < 8 || tid >= 24) ? ENC_NEG_INF : ENC_POS_INF;
        if (v != ident) {
            if (tid >= 8 && tid < 24) atomicMin(&ws[tid], v);
            else                      atomicMax(&ws[tid], v);
        }
    }
}

__device__ __forceinline__ float point_loss(float p0, float p1, int s, float z, float mu) {
    float m   = fmaxf(p0, p1);
    float lse = m + logf(expf(p0 - m) + expf(p1 - m));
    float lpt = ((s == 0) ? p0 : p1) - lse;
    float pt  = expf(lpt);
    float om  = 1.0f - pt;
    float loss = -lpt * om * om;           // LOSS_WEIGHT=ALPHA=1, GAMMA=2
    float d  = z - mu;
    float cf = (z <= mu) ? 50.0f : 3.125f; // 1/(2*0.1^2), 1/(2*0.4^2)
    float w  = expf(-d * d * cf);
    if (z > mu && d > 0.8f) w = 0.1f;      // d > 2*0.4 -> MIN_VAL
    return loss * w;
}

template <bool HAVE_ZC>
__global__ __launch_bounds__(THREADS) void k_loss(
        const float* __restrict__ pred, const float* __restrict__ coord,
        const int* __restrict__ segment, const int* __restrict__ offset,
        unsigned* __restrict__ ws, const float* __restrict__ zc,
        float* __restrict__ out, int n, int nb) {
    __shared__ float s_mu[8];
    __shared__ float s_part[THREADS / 64];
    __shared__ float s_c[HAVE_ZC ? 1 : TILE * 3];   // coord staging only in fallback
    const int tid = threadIdx.x;
    int roff[8];
    #pragma unroll
    for (int j = 0; j < 8; ++j) roff[j] = (j < nb) ? offset[j] : 0x7FFFFFFF;
    if (tid < 8) {
        unsigned ug = ws[tid], up = ws[8 + tid];
        float g = dec_f(ug), p = dec_f(up);
        if (ug == ENC_NEG_INF) g = dec_f(ws[16 + tid]);  // no ground -> z.min
        if (up == ENC_POS_INF) p = dec_f(ws[24 + tid]);  // no plant  -> z.max
        s_mu[tid] = g + (p - g) * 0.5f;
    }

    const int start = blockIdx.x * TILE;
    const int end   = min(n, start + TILE);
    int ba, bb;
    CNT_B(start, ba); CNT_B(end - 1, bb);
    const bool uni = (ba == bb);

    float lsum = 0.0f;
    if (end - start == TILE) {
        // 12 dense lane-contiguous loads, all independent -> max MLP, no strides
        float4 pf[4]; float2 zf[4]; int2 sf[4];
        const float4* pg4 = (const float4*)pred + ((size_t)start >> 1);
        #pragma unroll
        for (int k = 0; k < 4; ++k) pf[k] = pg4[tid + k * THREADS];
        const int2* sg2 = (const int2*)segment + (start >> 1);
        #pragma unroll
        for (int k = 0; k < 4; ++k) sf[k] = sg2[tid + k * THREADS];
        if (HAVE_ZC) {
            const float2* z2 = (const float2*)zc + (start >> 1);
            #pragma unroll
            for (int k = 0; k < 4; ++k) zf[k] = z2[tid + k * THREADS];
            __syncthreads();                     // s_mu visibility
        } else {
            const float4* cg4 = (const float4*)coord + (((size_t)start * 3) >> 2);
            float4* s_c4 = (float4*)s_c;
            #pragma unroll
            for (int k = 0; k < 6; ++k) s_c4[tid + k * THREADS] = cg4[tid + k * THREADS];
            __syncthreads();
            #pragma unroll
            for (int k = 0; k < 4; ++k) {
                int m = tid + k * THREADS;       // pair index: points 2m, 2m+1
                zf[k] = make_float2(s_c[6*m + 2], s_c[6*m + 5]);
            }
        }
        const float mu_u = s_mu[uni ? ba : 0];
        #pragma unroll
        for (int k = 0; k < 4; ++k) {
            const int m  = tid + k * THREADS;
            const int i0 = start + 2 * m;
            float mu0 = mu_u, mu1 = mu_u;
            if (!uni) {
                int b0, b1; CNT_B(i0, b0); CNT_B(i0 + 1, b1);
                mu0 = s_mu[b0]; mu1 = s_mu[b1];
            }
            lsum += point_loss(pf[k].x, pf[k].y, sf[k].x, zf[k].x, mu0);
            lsum += point_loss(pf[k].z, pf[k].w, sf[k].y, zf[k].y, mu1);
        }
    } else {
        __syncthreads();                          // s_mu visibility (match barrier count)
        const float2* pred2 = (const float2*)pred;
        for (int i = start + tid; i < end; i += THREADS) {
            float2 pp = pred2[i];
            float z = HAVE_ZC ? zc[i] : coord[3*i + 2];
            int s = segment[i], b; CNT_B(i, b);
            lsum += point_loss(pp.x, pp.y, s, z, s_mu[b]);
        }
    }

    #pragma unroll
    for (int off = 32; off > 0; off >>= 1) lsum += __shfl_down(lsum, off, 64);
    if ((tid & 63) == 0) s_part[tid >> 6] = lsum;
    __syncthreads();
    if (tid == 0) {
        float t = 0.0f;
        #pragma unroll
        for (int wv = 0; wv < THREADS / 64; ++wv) t += s_part[wv];
        double* acc = (double*)(ws + 32);
        atomicAdd(acc, (double)t);
        __threadfence();
        unsigned c = atomicAdd(&ws[34], 1u);
        if (c == (unsigned)gridDim.x - 1u) {       // last block finalizes
            double v = atomicAdd(acc, 0.0);        // coherent read via atomic
            out[0] = (float)(v / (double)n);
        }
    }
}

extern "C" void kernel_launch(void* const* d_in, const int* in_sizes, int n_in,
                              void* d_out, int out_size, void* d_ws, size_t ws_size,
                              hipStream_t stream) {
    const float* pred    = (const float*)d_in[0];
    const float* coord   = (const float*)d_in[1];
    const int*   segment = (const int*)d_in[2];
    const int*   offset  = (const int*)d_in[3];
    const int n  = in_sizes[2];
    const int nb = in_sizes[3];

    unsigned* ws = (unsigned*)d_ws;
    float*    zc = (float*)((char*)d_ws + 256);
    const bool have_zc = ws_size >= 256 + sizeof(float) * (size_t)n;
    const int  grid = (n + TILE - 1) / TILE;

    hipLaunchKernelGGL(k_init,  dim3(1), dim3(64), 0, stream, ws);
    hipLaunchKernelGGL(k_stats, dim3(grid), dim3(THREADS), 0, stream,
                       coord, segment, offset, ws, zc, n, nb, have_zc ? 1 : 0);
    if (have_zc)
        hipLaunchKernelGGL((k_loss<true>),  dim3(grid), dim3(THREADS), 0, stream,
                           pred, coord, segment, offset, ws, zc, (float*)d_out, n, nb);
    else
        hipLaunchKernelGGL((k_loss<false>), dim3(grid), dim3(THREADS), 0, stream,
                           pred, coord, segment, offset, ws, zc, (float*)d_out, n, nb);
}

// Round 6
// 141.605 us; speedup vs baseline: 1.7128x; 1.7128x over previous
//
#include <hip/hip_runtime.h>
#include <math.h>

#define THREADS 256
#define NBLOCKS 256   // 1 block/CU: R4 structure, minimal workgroup count
#define UNROLL  8

// ---- monotone float <-> uint encoding (order-preserving) ----
__device__ __forceinline__ unsigned enc_f(float f) {
    unsigned b = __float_as_uint(f);
    return (b & 0x80000000u) ? ~b : (b | 0x80000000u);
}
__device__ __forceinline__ float dec_f(unsigned u) {
    unsigned b = (u & 0x80000000u) ? (u ^ 0x80000000u) : ~u;
    return __uint_as_float(b);
}
#define ENC_NEG_INF 0x007FFFFFu   // enc(-inf): identity for max
#define ENC_POS_INF 0xFF800000u   // enc(+inf): identity for min

// ws layout (unsigned*): [0..7] gmax(max) | [8..15] pmin(min) | [16..23] zmin(min)
//                        [24..31] zmax(max) | [32..33] double acc | [34] done-counter

__global__ void k_init(unsigned* __restrict__ ws) {
    int t = threadIdx.x;
    if (t < 32) ws[t] = (t < 8 || t >= 24) ? ENC_NEG_INF : ENC_POS_INF;
    else if (t == 32) { *(double*)(ws + 32) = 0.0; ws[34] = 0u; }
}

#define FLUSH_TO(bb, g_, p_, mn_, mx_) do { \
    atomicMax(&s_stats[      (bb)], enc_f(g_));  \
    atomicMin(&s_stats[ 8  + (bb)], enc_f(p_));  \
    atomicMin(&s_stats[16  + (bb)], enc_f(mn_)); \
    atomicMax(&s_stats[24  + (bb)], enc_f(mx_)); } while (0)

__global__ __launch_bounds__(THREADS) void k_stats(
        const float* __restrict__ coord, const int* __restrict__ segment,
        const int* __restrict__ offset, unsigned* __restrict__ ws, int n, int nb) {
    __shared__ unsigned s_stats[32];
    const int tid = threadIdx.x;
    if (tid < 32) s_stats[tid] = (tid < 8 || tid >= 24) ? ENC_NEG_INF : ENC_POS_INF;
    int roff[8];                        // offsets in registers
    #pragma unroll
    for (int j = 0; j < 8; ++j) roff[j] = (j < nb) ? offset[j] : 0x7FFFFFFF;
    __syncthreads();

    const int chunk = (n + (int)gridDim.x - 1) / (int)gridDim.x;
    const int start = blockIdx.x * chunk;
    const int end   = min(n, start + chunk);

    float lg = -INFINITY, lp = INFINITY, lmn = INFINITY, lmx = -INFINITY;

    if (start < end) {
        int ba = 0, bb = 0;
        #pragma unroll
        for (int j = 0; j < 8; ++j) { ba += (start >= roff[j]); bb += ((end - 1) >= roff[j]); }
        if (ba == bb) {
            // ---- fast path: whole chunk in one cloud; coalesced scalar loads, 8x MLP ----
            int i = start + tid;
            for (; i + (UNROLL - 1) * THREADS < end; i += UNROLL * THREADS) {
                float z[UNROLL]; int s[UNROLL];
                #pragma unroll
                for (int k = 0; k < UNROLL; ++k) z[k] = coord[3 * (i + k * THREADS) + 2];
                #pragma unroll
                for (int k = 0; k < UNROLL; ++k) s[k] = segment[i + k * THREADS];
                #pragma unroll
                for (int k = 0; k < UNROLL; ++k) {
                    lmn = fminf(lmn, z[k]);
                    lmx = fmaxf(lmx, z[k]);
                    lg  = fmaxf(lg, (s[k] == 0) ? z[k] : -INFINITY);
                    lp  = fminf(lp, (s[k] != 0) ? z[k] : INFINITY);
                }
            }
            for (; i < end; i += THREADS) {
                float z = coord[3 * i + 2]; int s = segment[i];
                lmn = fminf(lmn, z); lmx = fmaxf(lmx, z);
                lg  = fmaxf(lg, (s == 0) ? z : -INFINITY);
                lp  = fminf(lp, (s != 0) ? z : INFINITY);
            }
            // wave reduce (block-uniform path: all lanes present)
            #pragma unroll
            for (int m = 32; m; m >>= 1) {
                lg  = fmaxf(lg,  __shfl_xor(lg,  m, 64));
                lp  = fminf(lp,  __shfl_xor(lp,  m, 64));
                lmn = fminf(lmn, __shfl_xor(lmn, m, 64));
                lmx = fmaxf(lmx, __shfl_xor(lmx, m, 64));
            }
            if ((tid & 63) == 0) FLUSH_TO(ba, lg, lp, lmn, lmx);
        } else {
            // ---- slow path (<= B-1 blocks): per-point batch tracking ----
            int curb = -1;
            for (int i = start + tid; i < end; i += THREADS) {
                float z = coord[3 * i + 2]; int s = segment[i], b = 0;
                #pragma unroll
                for (int j = 0; j < 8; ++j) b += (i >= roff[j]);
                if (b != curb) {
                    if (curb >= 0) FLUSH_TO(curb, lg, lp, lmn, lmx);
                    lg = -INFINITY; lp = INFINITY; lmn = INFINITY; lmx = -INFINITY;
                    curb = b;
                }
                lmn = fminf(lmn, z); lmx = fmaxf(lmx, z);
                if (s == 0) lg = fmaxf(lg, z); else lp = fminf(lp, z);
            }
            if (curb >= 0) FLUSH_TO(curb, lg, lp, lmn, lmx);
        }
    }
    __syncthreads();
    if (tid < 32) {
        unsigned v = s_stats[tid];
        unsigned ident = (tid < 8 || tid >= 24) ? ENC_NEG_INF : ENC_POS_INF;
        if (v != ident) {
            if (tid >= 8 && tid < 24) atomicMin(&ws[tid], v);
            else                      atomicMax(&ws[tid], v);
        }
    }
}

__device__ __forceinline__ float point_loss(float p0, float p1, int s, float z, float mu) {
    float m   = fmaxf(p0, p1);
    float lse = m + logf(expf(p0 - m) + expf(p1 - m));
    float lpt = ((s == 0) ? p0 : p1) - lse;
    float pt  = expf(lpt);
    float om  = 1.0f - pt;
    float loss = -lpt * om * om;           // LOSS_WEIGHT=ALPHA=1, GAMMA=2
    float d  = z - mu;
    float cf = (z <= mu) ? 50.0f : 3.125f; // 1/(2*0.1^2), 1/(2*0.4^2)
    float w  = expf(-d * d * cf);
    if (z > mu && d > 0.8f) w = 0.1f;      // d > 2*0.4 -> MIN_VAL
    return loss * w;
}

__global__ __launch_bounds__(THREADS) void k_loss(
        const float* __restrict__ pred, const float* __restrict__ coord,
        const int* __restrict__ segment, const int* __restrict__ offset,
        unsigned* __restrict__ ws, float* __restrict__ out, int n, int nb) {
    __shared__ float s_mu[8];
    __shared__ float s_part[THREADS / 64];
    const int tid = threadIdx.x;
    int roff[8];
    #pragma unroll
    for (int j = 0; j < 8; ++j) roff[j] = (j < nb) ? offset[j] : 0x7FFFFFFF;
    if (tid < 8) {
        unsigned ug = ws[tid], up = ws[8 + tid];
        float g = dec_f(ug), p = dec_f(up);
        if (ug == ENC_NEG_INF) g = dec_f(ws[16 + tid]);  // no ground -> z.min
        if (up == ENC_POS_INF) p = dec_f(ws[24 + tid]);  // no plant  -> z.max
        s_mu[tid] = g + (p - g) * 0.5f;
    }
    __syncthreads();

    const int chunk = (n + (int)gridDim.x - 1) / (int)gridDim.x;
    const int start = blockIdx.x * chunk;
    const int end   = min(n, start + chunk);
    const float2* pred2 = (const float2*)pred;

    float lsum = 0.0f;
    if (start < end) {
        int ba = 0, bb = 0;
        #pragma unroll
        for (int j = 0; j < 8; ++j) { ba += (start >= roff[j]); bb += ((end - 1) >= roff[j]); }
        if (ba == bb) {
            const float mu = s_mu[ba];       // hoisted, no LDS in hot loop
            int i = start + tid;
            for (; i + (UNROLL - 1) * THREADS < end; i += UNROLL * THREADS) {
                float z[UNROLL]; int s[UNROLL]; float2 pp[UNROLL];
                #pragma unroll
                for (int k = 0; k < UNROLL; ++k) pp[k] = pred2[i + k * THREADS];
                #pragma unroll
                for (int k = 0; k < UNROLL; ++k) z[k] = coord[3 * (i + k * THREADS) + 2];
                #pragma unroll
                for (int k = 0; k < UNROLL; ++k) s[k] = segment[i + k * THREADS];
                #pragma unroll
                for (int k = 0; k < UNROLL; ++k)
                    lsum += point_loss(pp[k].x, pp[k].y, s[k], z[k], mu);
            }
            for (; i < end; i += THREADS) {
                float2 pp = pred2[i];
                lsum += point_loss(pp.x, pp.y, segment[i], coord[3 * i + 2], mu);
            }
        } else {
            for (int i = start + tid; i < end; i += THREADS) {
                int b = 0;
                #pragma unroll
                for (int j = 0; j < 8; ++j) b += (i >= roff[j]);
                float2 pp = pred2[i];
                lsum += point_loss(pp.x, pp.y, segment[i], coord[3 * i + 2], s_mu[b]);
            }
        }
    }

    #pragma unroll
    for (int off = 32; off > 0; off >>= 1) lsum += __shfl_down(lsum, off, 64);
    if ((tid & 63) == 0) s_part[tid >> 6] = lsum;
    __syncthreads();
    if (tid == 0) {
        float t = 0.0f;
        #pragma unroll
        for (int wv = 0; wv < THREADS / 64; ++wv) t += s_part[wv];
        double* acc = (double*)(ws + 32);
        atomicAdd(acc, (double)t);
        __threadfence();
        unsigned c = atomicAdd(&ws[34], 1u);
        if (c == (unsigned)gridDim.x - 1u) {       // last block finalizes
            double v = atomicAdd(acc, 0.0);        // coherent read via atomic
            out[0] = (float)(v / (double)n);
        }
    }
}

extern "C" void kernel_launch(void* const* d_in, const int* in_sizes, int n_in,
                              void* d_out, int out_size, void* d_ws, size_t ws_size,
                              hipStream_t stream) {
    const float* pred    = (const float*)d_in[0];
    const float* coord   = (const float*)d_in[1];
    const int*   segment = (const int*)d_in[2];
    const int*   offset  = (const int*)d_in[3];
    const int n  = in_sizes[2];
    const int nb = in_sizes[3];

    unsigned* ws = (unsigned*)d_ws;

    hipLaunchKernelGGL(k_init,  dim3(1), dim3(64), 0, stream, ws);
    hipLaunchKernelGGL(k_stats, dim3(NBLOCKS), dim3(THREADS), 0, stream,
                       coord, segment, offset, ws, n, nb);
    hipLaunchKernelGGL(k_loss,  dim3(NBLOCKS), dim3(THREADS), 0, stream,
                       pred, coord, segment, offset, ws, (float*)d_out, n, nb);
}